// Round 6
// baseline (121.530 us; speedup 1.0000x reference)
//
#include <hip/hip_runtime.h>

// out = 0.5 * sum_over_pooled( maxpool4( x @ W^T + b ) )  -> (batch,) fp32
// x: (M=4096, K=2048) f32, W: (N=4096, K=2048) f32, b: (N,) f32, out: (M,) f32
// Strategy: cvt to bf16 in ws, then 256x256 8-phase pipelined MFMA GEMM using
// 32x32x16 MFMA (R3 sync structure: 2 barriers/phase, counted vmcnt(6) at
// tile boundary, setprio around MFMA, conflict-free XOR-swizzled LDS).
// Fused bias+maxpool4+rowsum epilogue with atomicAdd.

typedef float  f32x16  __attribute__((ext_vector_type(16)));
typedef short  bf16x8  __attribute__((ext_vector_type(8)));
typedef short  short4v __attribute__((ext_vector_type(4)));

__device__ __forceinline__ short f2bf(float f) {
    union { float f; unsigned u; } v; v.f = f;
    unsigned r = v.u + 0x7FFFu + ((v.u >> 16) & 1u);  // round-to-nearest-even
    return (short)(r >> 16);
}

__global__ void cvt_kernel(const float* __restrict__ x, const float* __restrict__ w,
                           short* __restrict__ out, long nx, long nw) {
    long total4 = (nx + nw) >> 2;
    long stride = (long)gridDim.x * blockDim.x;
    for (long i = (long)blockIdx.x * blockDim.x + threadIdx.x; i < total4; i += stride) {
        long e = i << 2;
        const float* src = (e < nx) ? (x + e) : (w + (e - nx));
        float4 v = *(const float4*)src;
        short4v s = { f2bf(v.x), f2bf(v.y), f2bf(v.z), f2bf(v.w) };
        *(short4v*)(out + e) = s;
    }
}

// LDS layout per 32KB tile buffer: chunk c = rows [8c..8c+7]; within chunk:
// (row&7)*128B + slot*16B where slot = q ^ (row&7), q = k-16B-index (0..7).
// Conflict-free ds_read_b128 (verified R3/R4: SQ_LDS_BANK_CONFLICT=0);
// staging source 128B-contiguous per 8 lanes; LDS dest linear for
// global_load_lds.
#define LDSOFF(rc, q) ((((rc) >> 3) << 9) + (((rc) & 7) << 6) + ((((q) ^ ((rc) & 7))) << 3))

__device__ __forceinline__ void stage_A(const short* __restrict__ G, short* lds,
                                        int blockRow, int K, int kt, int half,
                                        int wid, int lane) {
    // half 0: chunks {0..7,16..23} (rows 0-63,128-191); half 1: {8..15,24..31}
#pragma unroll
    for (int i = 0; i < 2; ++i) {
        int idx = wid * 2 + i;                                // 0..15
        int c   = (idx & 7) + ((idx >> 3) << 4) + (half << 3);
        int row = (c << 3) + (lane >> 3);
        int q   = (lane & 7) ^ (lane >> 3);                   // pre-swizzled src slot
        const short* src = G + (size_t)(blockRow + row) * K + kt * 64 + q * 8;
        __builtin_amdgcn_global_load_lds(
            (const __attribute__((address_space(1))) unsigned int*)src,
            (__attribute__((address_space(3))) unsigned int*)(lds + c * 512),
            16, 0, 0);
    }
}

__device__ __forceinline__ void stage_B(const short* __restrict__ G, short* lds,
                                        int blockCol, int K, int kt, int half,
                                        int wid, int lane) {
    // half 0: chunks {0-3,8-11,16-19,24-27} (cols 0-31,64-95,...); half 1: +4
#pragma unroll
    for (int i = 0; i < 2; ++i) {
        int idx = wid * 2 + i;
        int c   = ((idx >> 2) << 3) + (idx & 3) + (half << 2);
        int row = (c << 3) + (lane >> 3);
        int q   = (lane & 7) ^ (lane >> 3);
        const short* src = G + (size_t)(blockCol + row) * K + kt * 64 + q * 8;
        __builtin_amdgcn_global_load_lds(
            (const __attribute__((address_space(1))) unsigned int*)src,
            (__attribute__((address_space(3))) unsigned int*)(lds + c * 512),
            16, 0, 0);
    }
}

__global__ __launch_bounds__(512, 2) void gemm_pool_kernel(
    const short* __restrict__ X, const short* __restrict__ W,
    const float* __restrict__ bias, float* __restrict__ out, int K)
{
    __shared__ short As[32768];   // 64 KB: 2 x (256 rows x 64 k)
    __shared__ short Bs[32768];   // 64 KB

    const int tid  = threadIdx.x;
    const int lane = tid & 63;
    const int wid  = tid >> 6;     // 0..7
    const int wr   = wid >> 2;     // 0..1  (wave row: 128 rows each)
    const int wc   = wid & 3;      // 0..3  (wave col: 64 cols each)
    const int lo32 = lane & 31;    // 32x32 frag: row/col within block
    const int hi32 = lane >> 5;    // 32x32 frag: k-octet selector

    // XCD-aware bijective block swizzle (measured neutral; kept — demand BW
    // rises toward the L2-sensitive regime as the kernel speeds up).
    const int nwg  = gridDim.x * gridDim.y;        // 256 (divisible by 8)
    const int bid  = blockIdx.y * gridDim.x + blockIdx.x;
    const int wgid = (bid & 7) * (nwg >> 3) + (bid >> 3);
    const int brow = (wgid / gridDim.x) * 256;
    const int bcol = (wgid % gridDim.x) * 256;
    const int nk   = K >> 6;       // 64-wide K tiles (assumes nk >= 4)

    f32x16 acc[4][2] = {};         // [m-block 32 rows][n-block 32 cols]
    bf16x8 a[2][4], b[4];          // one A-half (2 m-blocks x 4 ks), one B-half

    // Prologue: tile-0 fully, then tile-1 minus its B0 (staged at t=0 P1).
    stage_A(X, As,         brow, K, 0, 0, wid, lane);   // A0(0)
    stage_B(W, Bs,         bcol, K, 0, 0, wid, lane);   // B0(0)
    stage_B(W, Bs,         bcol, K, 0, 1, wid, lane);   // B1(0)
    stage_A(X, As,         brow, K, 0, 1, wid, lane);   // A1(0)
    stage_A(X, As + 16384, brow, K, 1, 0, wid, lane);   // A0(1)
    stage_B(W, Bs + 16384, bcol, K, 1, 1, wid, lane);   // B1(1)
    stage_A(X, As + 16384, brow, K, 1, 1, wid, lane);   // A1(1)
    asm volatile("s_waitcnt vmcnt(6)" ::: "memory");    // tile-0 complete
    __builtin_amdgcn_s_barrier();

    for (int t = 0; t < nk; ++t) {
        short* Ab = As + ((t & 1) << 14);
        short* Bb = Bs + ((t & 1) << 14);
        short* Bn = Bs + (((t & 1) ^ 1) << 14);

        // ---- P1: reads a0 (8) + b0 (4); stage B0(t+1)->other buf; MFMA (0,0)
#pragma unroll
        for (int mi = 0; mi < 2; ++mi)
#pragma unroll
            for (int ks = 0; ks < 4; ++ks) {
                int rc = wr * 128 + mi * 32 + lo32;
                a[mi][ks] = *(const bf16x8*)(Ab + LDSOFF(rc, ks * 2 + hi32));
            }
#pragma unroll
        for (int ks = 0; ks < 4; ++ks) {
            int rc = wc * 64 + lo32;
            b[ks] = *(const bf16x8*)(Bb + LDSOFF(rc, ks * 2 + hi32));
        }
        if (t + 1 < nk) stage_B(W, Bn, bcol, K, t + 1, 0, wid, lane);
        __builtin_amdgcn_s_barrier();
        __builtin_amdgcn_s_setprio(1);
#pragma unroll
        for (int ks = 0; ks < 4; ++ks) {
            acc[0][0] = __builtin_amdgcn_mfma_f32_32x32x16_bf16(a[0][ks], b[ks], acc[0][0], 0, 0, 0);
            acc[1][0] = __builtin_amdgcn_mfma_f32_32x32x16_bf16(a[1][ks], b[ks], acc[1][0], 0, 0, 0);
        }
        __builtin_amdgcn_s_setprio(0);
        __builtin_amdgcn_s_barrier();

        // ---- P2: reads b1 (4); stage A0(t+2)->same buf; MFMA (0,1)
#pragma unroll
        for (int ks = 0; ks < 4; ++ks) {
            int rc = wc * 64 + 32 + lo32;
            b[ks] = *(const bf16x8*)(Bb + LDSOFF(rc, ks * 2 + hi32));
        }
        if (t + 2 < nk) stage_A(X, Ab, brow, K, t + 2, 0, wid, lane);
        __builtin_amdgcn_s_barrier();
        __builtin_amdgcn_s_setprio(1);
#pragma unroll
        for (int ks = 0; ks < 4; ++ks) {
            acc[0][1] = __builtin_amdgcn_mfma_f32_32x32x16_bf16(a[0][ks], b[ks], acc[0][1], 0, 0, 0);
            acc[1][1] = __builtin_amdgcn_mfma_f32_32x32x16_bf16(a[1][ks], b[ks], acc[1][1], 0, 0, 0);
        }
        __builtin_amdgcn_s_setprio(0);
        __builtin_amdgcn_s_barrier();

        // ---- P3: reads a1 (8); stage B1(t+2); MFMA (1,1)
#pragma unroll
        for (int mi = 0; mi < 2; ++mi)
#pragma unroll
            for (int ks = 0; ks < 4; ++ks) {
                int rc = wr * 128 + 64 + mi * 32 + lo32;
                a[mi][ks] = *(const bf16x8*)(Ab + LDSOFF(rc, ks * 2 + hi32));
            }
        if (t + 2 < nk) stage_B(W, Bb, bcol, K, t + 2, 1, wid, lane);
        __builtin_amdgcn_s_barrier();
        __builtin_amdgcn_s_setprio(1);
#pragma unroll
        for (int ks = 0; ks < 4; ++ks) {
            acc[2][1] = __builtin_amdgcn_mfma_f32_32x32x16_bf16(a[0][ks], b[ks], acc[2][1], 0, 0, 0);
            acc[3][1] = __builtin_amdgcn_mfma_f32_32x32x16_bf16(a[1][ks], b[ks], acc[3][1], 0, 0, 0);
        }
        __builtin_amdgcn_s_setprio(0);
        __builtin_amdgcn_s_barrier();

        // ---- P4: re-reads b0 (4); stage A1(t+2); MFMA (1,0)
#pragma unroll
        for (int ks = 0; ks < 4; ++ks) {
            int rc = wc * 64 + lo32;
            b[ks] = *(const bf16x8*)(Bb + LDSOFF(rc, ks * 2 + hi32));
        }
        if (t + 2 < nk) stage_A(X, Ab, brow, K, t + 2, 1, wid, lane);
        __builtin_amdgcn_s_barrier();
        __builtin_amdgcn_s_setprio(1);
#pragma unroll
        for (int ks = 0; ks < 4; ++ks) {
            acc[2][0] = __builtin_amdgcn_mfma_f32_32x32x16_bf16(a[0][ks], b[ks], acc[2][0], 0, 0, 0);
            acc[3][0] = __builtin_amdgcn_mfma_f32_32x32x16_bf16(a[1][ks], b[ks], acc[3][0], 0, 0, 0);
        }
        __builtin_amdgcn_s_setprio(0);
        // Tile boundary: counted drain (keep newest 3 half-tiles = 6 loads in
        // flight), then barrier -> cross-wave happens-before for next tile.
        if (t == nk - 2)      asm volatile("s_waitcnt vmcnt(0)" ::: "memory");
        else if (t < nk - 2)  asm volatile("s_waitcnt vmcnt(6)" ::: "memory");
        __builtin_amdgcn_s_barrier();
    }

    // Epilogue: bias + maxpool4(cols) + rowsum, fused.
    // 32x32 C/D frag mapping: col = lane&31, row = (reg&3)+8*(reg>>2)+4*(lane>>5)
    // [m74/m101-verified]. Pool groups = 4 consecutive cols = lanes (lo32&3).
    float bias_n[2];
#pragma unroll
    for (int nn = 0; nn < 2; ++nn)
        bias_n[nn] = bias[bcol + wc * 64 + nn * 32 + lo32];

#pragma unroll
    for (int mm = 0; mm < 4; ++mm) {
#pragma unroll
        for (int r = 0; r < 16; ++r) {
            float part = 0.f;
#pragma unroll
            for (int nn = 0; nn < 2; ++nn) {
                float v = acc[mm][nn][r] + bias_n[nn];
                v = fmaxf(v, __shfl_xor(v, 1));   // pool across col bit 0
                v = fmaxf(v, __shfl_xor(v, 2));   // pool across col bit 1
                part += v;                        // lane holds pooled[(lo32>>2)]
            }
            part += __shfl_xor(part, 4);          // sum the 8 pool groups
            part += __shfl_xor(part, 8);
            part += __shfl_xor(part, 16);
            if (lo32 == 0)
                atomicAdd(&out[brow + wr * 128 + mm * 32 +
                               (r & 3) + 8 * (r >> 2) + 4 * hi32], part * 0.5f);
        }
    }
}

extern "C" void kernel_launch(void* const* d_in, const int* in_sizes, int n_in,
                              void* d_out, int out_size, void* d_ws, size_t ws_size,
                              hipStream_t stream) {
    const float* x = (const float*)d_in[0];
    const float* W = (const float*)d_in[1];
    const float* b = (const float*)d_in[2];
    float* out = (float*)d_out;

    const int N = in_sizes[2];             // out_f = 4096
    const int K = in_sizes[1] / N;         // in_f  = 2048
    const int M = in_sizes[0] / K;         // batch = 4096

    // Atomics accumulate into out -> must zero every call (graph replays).
    hipMemsetAsync(out, 0, (size_t)out_size * sizeof(float), stream);

    short* xb = (short*)d_ws;
    short* wb = xb + in_sizes[0];
    cvt_kernel<<<2048, 256, 0, stream>>>(x, W, (short*)d_ws,
                                         (long)in_sizes[0], (long)in_sizes[1]);

    dim3 grid(N / 256, M / 256);           // 16x16 = 256 blocks = 1/CU
    gemm_pool_kernel<<<grid, 512, 0, stream>>>(xb, wb, b, out, K);
}

// Round 7
// 98.345 us; speedup vs baseline: 1.2358x; 1.2358x over previous
//
#include <hip/hip_runtime.h>

// out = 0.5 * sum_over_pooled( maxpool4( x @ W^T + b ) )  -> (batch,) fp32
// x: (M=4096, K=2048) f32, W: (N=4096, K=2048) f32, b: (N,) f32, out: (M,) f32
// Strategy: cvt to bf16 in ws, then 256x128-tile BK=32 MFMA GEMM, triple-
// buffered LDS (72KB -> 2 blocks/CU for cross-block pipe overlap), ONE
// barrier per K-tile, depth-2 prefetch with counted vmcnt(3), conflict-free
// paired-row XOR swizzle. Fused bias+maxpool4+rowsum epilogue with atomicAdd.

typedef float  f32x4   __attribute__((ext_vector_type(4)));
typedef short  bf16x8  __attribute__((ext_vector_type(8)));
typedef short  short4v __attribute__((ext_vector_type(4)));

__device__ __forceinline__ short f2bf(float f) {
    union { float f; unsigned u; } v; v.f = f;
    unsigned r = v.u + 0x7FFFu + ((v.u >> 16) & 1u);  // round-to-nearest-even
    return (short)(r >> 16);
}

__global__ void cvt_kernel(const float* __restrict__ x, const float* __restrict__ w,
                           short* __restrict__ out, long nx, long nw) {
    long total4 = (nx + nw) >> 2;
    long stride = (long)gridDim.x * blockDim.x;
    for (long i = (long)blockIdx.x * blockDim.x + threadIdx.x; i < total4; i += stride) {
        long e = i << 2;
        const float* src = (e < nx) ? (x + e) : (w + (e - nx));
        float4 v = *(const float4*)src;
        short4v s = { f2bf(v.x), f2bf(v.y), f2bf(v.z), f2bf(v.w) };
        *(short4v*)(out + e) = s;
    }
}

// LDS layout (BK=32): chunk = 16 rows x 64B = 1KB. Within a chunk, row r,
// k-slice q (16B, q=0..3) sits at byte  (r>>1)*128 + slot*16  with
// slot = (q + ((r&1)<<2)) ^ ((r>>1)&7).
// -> For a fragment ds_read_b128 (16 lanes = 16 rows, fixed q), every
//    simultaneous 8-lane group covers all 8 slots of a 128B bank period
//    exactly once: conflict-free. Staging writes are linear per lane
//    (global_load_lds); the per-lane GLOBAL source applies the inverse:
//    t = (l&7)^((l>>3)&7); row = 2*(l>>3)+(t>>2); q = t&3.

__device__ __forceinline__ void stage_chunk(const short* __restrict__ G, short* lds,
                                            int rowBase, int K, int kt, int c,
                                            int grow, int gq) {
    const short* src = G + (size_t)(rowBase + c * 16 + grow) * K + kt * 32 + gq * 8;
    __builtin_amdgcn_global_load_lds(
        (const __attribute__((address_space(1))) unsigned int*)src,
        (__attribute__((address_space(3))) unsigned int*)(lds + c * 512),
        16, 0, 0);
}

__global__ __launch_bounds__(512, 4) void gemm_pool_kernel(
    const short* __restrict__ X, const short* __restrict__ W,
    const float* __restrict__ bias, float* __restrict__ out, int K)
{
    __shared__ short As[3 * 8192];   // 3 bufs x (256 rows x 32 k) = 48 KB
    __shared__ short Bs[3 * 4096];   // 3 bufs x (128 rows x 32 k) = 24 KB

    const int tid  = threadIdx.x;
    const int lane = tid & 63;
    const int wid  = tid >> 6;     // 0..7
    const int wrM  = wid >> 1;     // 0..3  (wave row: 64 out-rows each)
    const int wcN  = wid & 1;      // 0..1  (wave col: 64 out-cols each)
    const int hi   = lane >> 4;    // k-slice q for fragments (0..3)
    const int lo   = lane & 15;

    // XCD-aware bijective block swizzle (nwg=512, divisible by 8).
    const int bid  = blockIdx.x;
    const int wgid = (bid & 7) * 64 + (bid >> 3);
    const int brow = (wgid >> 5) * 256;   // 16 M-tiles
    const int bcol = (wgid & 31) * 128;   // 32 N-tiles
    const int nk   = K >> 5;              // BK=32 K-tiles (assumes nk >= 4)

    // staging lane mapping (inverse of the LDS swizzle)
    const int tt   = (lane & 7) ^ ((lane >> 3) & 7);
    const int grow = ((lane >> 3) << 1) + (tt >> 2);
    const int gq   = tt & 3;

    // fragment ds_read offset within a chunk (shorts): row=lo, slice=hi
    const int rsub = ((lo >> 1) << 6) +
                     ((((hi + ((lo & 1) << 2)) ^ ((lo >> 1) & 7))) << 3);

    f32x4 acc[4][4] = {};

    // Prologue: stage tiles 0 and 1; drain tile 0 (keep tile 1's 3 in flight).
    {
        stage_chunk(X, As,        brow, K, 0, wid,     grow, gq);
        stage_chunk(X, As,        brow, K, 0, wid + 8, grow, gq);
        stage_chunk(W, Bs,        bcol, K, 0, wid,     grow, gq);
        stage_chunk(X, As + 8192, brow, K, 1, wid,     grow, gq);
        stage_chunk(X, As + 8192, brow, K, 1, wid + 8, grow, gq);
        stage_chunk(W, Bs + 4096, bcol, K, 1, wid,     grow, gq);
    }
    asm volatile("s_waitcnt vmcnt(3)" ::: "memory");
    __builtin_amdgcn_s_barrier();

    int cur = 0;                   // t % 3
    for (int t = 0; t < nk; ++t) {
        short* Ab = As + cur * 8192;
        short* Bb = Bs + cur * 4096;
        int nxt = cur + 2; if (nxt >= 3) nxt -= 3;   // (t+2) % 3

        bf16x8 a[4], b[4];
#pragma unroll
        for (int m = 0; m < 4; ++m)
            a[m] = *(const bf16x8*)(Ab + (wrM * 4 + m) * 512 + rsub);
#pragma unroll
        for (int n = 0; n < 4; ++n)
            b[n] = *(const bf16x8*)(Bb + (wcN * 4 + n) * 512 + rsub);

        // Depth-2 prefetch into buffer (t+2)%3. WAR-safe: that buffer's last
        // readers were tile t-1, whose reads drained before every wave
        // crossed the barrier at the end of t-1 (MFMA lgkm dependency).
        if (t + 2 < nk) {
            stage_chunk(X, As + nxt * 8192, brow, K, t + 2, wid,     grow, gq);
            stage_chunk(X, As + nxt * 8192, brow, K, t + 2, wid + 8, grow, gq);
            stage_chunk(W, Bs + nxt * 4096, bcol, K, t + 2, wid,     grow, gq);
        }

        __builtin_amdgcn_s_setprio(1);
#pragma unroll
        for (int m = 0; m < 4; ++m)
#pragma unroll
            for (int n = 0; n < 4; ++n)
                acc[m][n] = __builtin_amdgcn_mfma_f32_16x16x32_bf16(
                    a[m], b[n], acc[m][n], 0, 0, 0);
        __builtin_amdgcn_s_setprio(0);

        // Boundary: drain tile t+1's 3 loads (keep t+2's 3 in flight), then
        // barrier -> cross-wave happens-before for tile t+1's reads.
        if (t == nk - 2)      asm volatile("s_waitcnt vmcnt(0)" ::: "memory");
        else if (t < nk - 2)  asm volatile("s_waitcnt vmcnt(3)" ::: "memory");
        __builtin_amdgcn_s_barrier();

        cur += 1; if (cur >= 3) cur -= 3;
    }

    // Epilogue: bias + maxpool4(cols) + rowsum, fused.
    // C/D frag mapping: col = lane&15, row = (lane>>4)*4 + reg  [m89-verified]
    float bias_n[4];
#pragma unroll
    for (int n = 0; n < 4; ++n)
        bias_n[n] = bias[bcol + wcN * 64 + n * 16 + lo];

#pragma unroll
    for (int m = 0; m < 4; ++m) {
#pragma unroll
        for (int j = 0; j < 4; ++j) {
            float part = 0.f;
#pragma unroll
            for (int n = 0; n < 4; ++n) {
                float v = acc[m][n][j] + bias_n[n];
                v = fmaxf(v, __shfl_xor(v, 1));   // pool across col bit 0
                v = fmaxf(v, __shfl_xor(v, 2));   // pool across col bit 1
                part += v;                        // lane holds pooled[(lo>>2)]
            }
            part += __shfl_xor(part, 4);          // sum the 4 pool groups
            part += __shfl_xor(part, 8);
            if (lo == 0)
                atomicAdd(&out[brow + wrM * 64 + m * 16 + hi * 4 + j], part * 0.5f);
        }
    }
}

extern "C" void kernel_launch(void* const* d_in, const int* in_sizes, int n_in,
                              void* d_out, int out_size, void* d_ws, size_t ws_size,
                              hipStream_t stream) {
    const float* x = (const float*)d_in[0];
    const float* W = (const float*)d_in[1];
    const float* b = (const float*)d_in[2];
    float* out = (float*)d_out;

    const int N = in_sizes[2];             // out_f = 4096
    const int K = in_sizes[1] / N;         // in_f  = 2048
    const int M = in_sizes[0] / K;         // batch = 4096

    // Atomics accumulate into out -> must zero every call (graph replays).
    hipMemsetAsync(out, 0, (size_t)out_size * sizeof(float), stream);

    short* xb = (short*)d_ws;
    short* wb = xb + in_sizes[0];
    cvt_kernel<<<2048, 256, 0, stream>>>(x, W, (short*)d_ws,
                                         (long)in_sizes[0], (long)in_sizes[1]);

    const int nblk = (M / 256) * (N / 128);   // 512 blocks = 2/CU
    gemm_pool_kernel<<<dim3(nblk), 512, 0, stream>>>(xb, wb, b, out, K);
}

// Round 9
// 95.040 us; speedup vs baseline: 1.2787x; 1.0348x over previous
//
#include <hip/hip_runtime.h>

// out = 0.5 * sum_over_pooled( maxpool4( x @ W^T + b ) )  -> (batch,) fp32
// x: (M=4096, K=2048) f32, W: (N=4096, K=2048) f32, b: (N,) f32, out: (M,) f32
// Strategy: cvt to bf16 in ws; 256x256 BK=64 8-wave MFMA GEMM, 2-K-tiles-per-
// iteration unrolled loop so ALL ds_read addresses are base+compile-time-
// immediate (4 base VGPRs, zero address VALU in the loop), running global
// pointers for staging (zero muls), pre-barrier lgkmcnt(0), counted vmcnt(6)
// per tile, setprio around MFMA, conflict-free XOR-swizzled LDS.
// Fused bias+maxpool4+rowsum epilogue with atomicAdd.

typedef float  f32x4   __attribute__((ext_vector_type(4)));
typedef short  bf16x8  __attribute__((ext_vector_type(8)));
typedef short  short4v __attribute__((ext_vector_type(4)));

__device__ __forceinline__ short f2bf(float f) {
    union { float f; unsigned u; } v; v.f = f;
    unsigned r = v.u + 0x7FFFu + ((v.u >> 16) & 1u);  // round-to-nearest-even
    return (short)(r >> 16);
}

__global__ void cvt_kernel(const float* __restrict__ x, const float* __restrict__ w,
                           short* __restrict__ out, long nx, long nw) {
    long total4 = (nx + nw) >> 2;
    long stride = (long)gridDim.x * blockDim.x;
    for (long i = (long)blockIdx.x * blockDim.x + threadIdx.x; i < total4; i += stride) {
        long e = i << 2;
        const float* src = (e < nx) ? (x + e) : (w + (e - nx));
        float4 v = *(const float4*)src;
        short4v s = { f2bf(v.x), f2bf(v.y), f2bf(v.z), f2bf(v.w) };
        *(short4v*)(out + e) = s;
    }
}

// LDS layout per 32KB buffer: row r (0..255), k-slice q (0..7 sixteen-byte
// slices): short-offset = (r>>3)*512 + (r&7)*64 + (q^(r&7))*8.  Fragment
// ds_read_b128 groups cover all 8 slots of each 128B period -> conflict-free
// (verified R3/R4: SQ_LDS_BANK_CONFLICT=0). Staging is linear per chunk
// (chunk = 8 rows = 1KB = one wave-wide global_load_lds); the global source
// applies the inverse swizzle: row = c*8 + (l>>3), q = (l&7)^(l>>3).
//
// Byte-offset audit (fixed R8 bug):
//   mm (+16 rows)  -> +2 chunks  = 1024 shorts = 2048 B   -> mm*2048
//   nn (+16 rows)  -> +2 chunks  = 1024 shorts = 2048 B   -> nn*2048
//   b half (+32 r) -> +4 chunks  = 2048 shorts = 4096 B   -> +4096
//   a half (+64 r) -> +8 chunks  = 4096 shorts = 8192 B   -> +8192  (was 16384: BUG)
//   buffer stride  -> 16384 shorts = 32768 B              -> BUF*32768

#define GLL(gp, ldsp)                                                          \
    __builtin_amdgcn_global_load_lds(                                          \
        (const __attribute__((address_space(1))) unsigned int*)(gp),           \
        (__attribute__((address_space(3))) unsigned int*)(ldsp), 16, 0, 0)

__global__ __launch_bounds__(512, 2) void gemm_pool_kernel(
    const short* __restrict__ X, const short* __restrict__ W,
    const float* __restrict__ bias, float* __restrict__ out, int K)
{
    __shared__ short As[32768];   // 2 bufs x (256 rows x 64 k) = 64 KB
    __shared__ short Bs[32768];   // 64 KB

    const int tid  = threadIdx.x;
    const int lane = tid & 63;
    const int wid  = tid >> 6;     // 0..7
    const int wr   = wid >> 2;     // 0..1  (wave rows: 128 each)
    const int wc   = wid & 3;      // 0..3  (wave cols: 64 each)
    const int hi   = lane >> 4;    // frag k-slice part
    const int lo   = lane & 15;    // frag row part

    // XCD-aware bijective block swizzle (nwg = 256, divisible by 8).
    const int nwg  = gridDim.x * gridDim.y;
    const int bid  = blockIdx.y * gridDim.x + blockIdx.x;
    const int wgid = (bid & 7) * (nwg >> 3) + (bid >> 3);
    const int brow = (wgid / gridDim.x) * 256;
    const int bcol = (wgid % gridDim.x) * 256;
    const int nk   = K >> 6;       // BK=64 tiles; requires nk even, >= 4

    // ---- thread-constant ds_read bases (all loop reads = base + imm) ----
    const int slot0 = hi ^ (lo & 7);
    const int slot1 = (4 + hi) ^ (lo & 7);
    const char* baseA0 = (const char*)As + (((wr * 16 + (lo >> 3)) * 512 + (lo & 7) * 64 + slot0 * 8) << 1);
    const char* baseA1 = (const char*)As + (((wr * 16 + (lo >> 3)) * 512 + (lo & 7) * 64 + slot1 * 8) << 1);
    const char* baseB0 = (const char*)Bs + (((wc * 8  + (lo >> 3)) * 512 + (lo & 7) * 64 + slot0 * 8) << 1);
    const char* baseB1 = (const char*)Bs + (((wc * 8  + (lo >> 3)) * 512 + (lo & 7) * 64 + slot1 * 8) << 1);

    // ---- staging chunk ids and running global pointers (kt = 0) ----
    const int idx0 = wid * 2, idx1 = wid * 2 + 1;
    const int cA00 = (idx0 & 7) + ((idx0 >> 3) << 4), cA10 = (idx1 & 7) + ((idx1 >> 3) << 4);
    const int cA01 = cA00 + 8,                         cA11 = cA10 + 8;
    const int cB00 = ((idx0 >> 2) << 3) + (idx0 & 3),  cB10 = ((idx1 >> 2) << 3) + (idx1 & 3);
    const int cB01 = cB00 + 4,                         cB11 = cB10 + 4;
    const int grow = lane >> 3;
    const int gq8  = ((lane & 7) ^ (lane >> 3)) * 8;

    const short* pA00 = X + (size_t)(brow + cA00 * 8 + grow) * K + gq8;
    const short* pA10 = X + (size_t)(brow + cA10 * 8 + grow) * K + gq8;
    const short* pA01 = X + (size_t)(brow + cA01 * 8 + grow) * K + gq8;
    const short* pA11 = X + (size_t)(brow + cA11 * 8 + grow) * K + gq8;
    const short* pB00 = W + (size_t)(bcol + cB00 * 8 + grow) * K + gq8;
    const short* pB10 = W + (size_t)(bcol + cB10 * 8 + grow) * K + gq8;
    const short* pB01 = W + (size_t)(bcol + cB01 * 8 + grow) * K + gq8;
    const short* pB11 = W + (size_t)(bcol + cB11 * 8 + grow) * K + gq8;

    f32x4 acc[8][4] = {};
    bf16x8 a[4][2], b[2][2];

    // ---- prologue: tile 0 fully + tile 1 minus its B0 (staged at t=0 P1) ----
    GLL(pA00, As + cA00 * 512); GLL(pA10, As + cA10 * 512);               // A0(0)
    GLL(pB00, Bs + cB00 * 512); GLL(pB10, Bs + cB10 * 512);               // B0(0)
    GLL(pB01, Bs + cB01 * 512); GLL(pB11, Bs + cB11 * 512);               // B1(0)
    GLL(pA01, As + cA01 * 512); GLL(pA11, As + cA11 * 512);               // A1(0)
    GLL(pA00 + 64, As + 16384 + cA00 * 512); GLL(pA10 + 64, As + 16384 + cA10 * 512); // A0(1)
    GLL(pB01 + 64, Bs + 16384 + cB01 * 512); GLL(pB11 + 64, Bs + 16384 + cB11 * 512); // B1(1)
    GLL(pA01 + 64, As + 16384 + cA01 * 512); GLL(pA11 + 64, As + 16384 + cA11 * 512); // A1(1)
    pA00 += 128; pA10 += 128; pA01 += 128; pA11 += 128;
    pB00 += 128; pB10 += 128; pB01 += 128; pB11 += 128;   // now at kt = 2
    asm volatile("s_waitcnt vmcnt(6)" ::: "memory");       // tile-0 complete
    __builtin_amdgcn_s_barrier();

    // Invariant at start of tile T: ptrs point at kt = T+2; B0 stage uses -64.
#define TILE_BODY(T, BUF)                                                          \
    {                                                                              \
        /* P1: read a0(8)+b0(4); stage B0(T+1)->other buf; MFMA (0,0) */           \
        _Pragma("unroll")                                                          \
        for (int mm = 0; mm < 4; ++mm) {                                           \
            a[mm][0] = *(const bf16x8*)(baseA0 + (BUF)*32768 + mm*2048);           \
            a[mm][1] = *(const bf16x8*)(baseA1 + (BUF)*32768 + mm*2048);           \
        }                                                                          \
        _Pragma("unroll")                                                          \
        for (int nn = 0; nn < 2; ++nn) {                                           \
            b[nn][0] = *(const bf16x8*)(baseB0 + (BUF)*32768 + nn*2048);           \
            b[nn][1] = *(const bf16x8*)(baseB1 + (BUF)*32768 + nn*2048);           \
        }                                                                          \
        if ((T) + 1 < nk) {                                                        \
            GLL(pB00 - 64, Bs + (1-(BUF))*16384 + cB00*512);                       \
            GLL(pB10 - 64, Bs + (1-(BUF))*16384 + cB10*512);                       \
        }                                                                          \
        asm volatile("s_waitcnt lgkmcnt(0)" ::: "memory");                         \
        __builtin_amdgcn_s_barrier();                                              \
        __builtin_amdgcn_s_setprio(1);                                             \
        _Pragma("unroll")                                                          \
        for (int mm = 0; mm < 4; ++mm)                                             \
            _Pragma("unroll")                                                      \
            for (int nn = 0; nn < 2; ++nn)                                         \
                _Pragma("unroll")                                                  \
                for (int kk = 0; kk < 2; ++kk)                                     \
                    acc[mm][nn] = __builtin_amdgcn_mfma_f32_16x16x32_bf16(         \
                        a[mm][kk], b[nn][kk], acc[mm][nn], 0, 0, 0);               \
        __builtin_amdgcn_s_setprio(0);                                             \
        __builtin_amdgcn_s_barrier();                                              \
        /* P2: read b1(4); stage A0(T+2)->same buf; MFMA (0,1) */                  \
        _Pragma("unroll")                                                          \
        for (int nn = 0; nn < 2; ++nn) {                                           \
            b[nn][0] = *(const bf16x8*)(baseB0 + (BUF)*32768 + nn*2048 + 4096);    \
            b[nn][1] = *(const bf16x8*)(baseB1 + (BUF)*32768 + nn*2048 + 4096);    \
        }                                                                          \
        if ((T) + 2 < nk) {                                                        \
            GLL(pA00, As + (BUF)*16384 + cA00*512);                                \
            GLL(pA10, As + (BUF)*16384 + cA10*512);                                \
        }                                                                          \
        asm volatile("s_waitcnt lgkmcnt(0)" ::: "memory");                         \
        __builtin_amdgcn_s_barrier();                                              \
        __builtin_amdgcn_s_setprio(1);                                             \
        _Pragma("unroll")                                                          \
        for (int mm = 0; mm < 4; ++mm)                                             \
            _Pragma("unroll")                                                      \
            for (int nn = 0; nn < 2; ++nn)                                         \
                _Pragma("unroll")                                                  \
                for (int kk = 0; kk < 2; ++kk)                                     \
                    acc[mm][2+nn] = __builtin_amdgcn_mfma_f32_16x16x32_bf16(       \
                        a[mm][kk], b[nn][kk], acc[mm][2+nn], 0, 0, 0);             \
        __builtin_amdgcn_s_setprio(0);                                             \
        __builtin_amdgcn_s_barrier();                                              \
        /* P3: read a1(8) [+8192 B = 64 rows]; stage B1(T+2); MFMA (1,1) */        \
        _Pragma("unroll")                                                          \
        for (int mm = 0; mm < 4; ++mm) {                                           \
            a[mm][0] = *(const bf16x8*)(baseA0 + (BUF)*32768 + mm*2048 + 8192);    \
            a[mm][1] = *(const bf16x8*)(baseA1 + (BUF)*32768 + mm*2048 + 8192);    \
        }                                                                          \
        if ((T) + 2 < nk) {                                                        \
            GLL(pB01, Bs + (BUF)*16384 + cB01*512);                                \
            GLL(pB11, Bs + (BUF)*16384 + cB11*512);                                \
        }                                                                          \
        asm volatile("s_waitcnt lgkmcnt(0)" ::: "memory");                         \
        __builtin_amdgcn_s_barrier();                                              \
        __builtin_amdgcn_s_setprio(1);                                             \
        _Pragma("unroll")                                                          \
        for (int mm = 0; mm < 4; ++mm)                                             \
            _Pragma("unroll")                                                      \
            for (int nn = 0; nn < 2; ++nn)                                         \
                _Pragma("unroll")                                                  \
                for (int kk = 0; kk < 2; ++kk)                                     \
                    acc[4+mm][2+nn] = __builtin_amdgcn_mfma_f32_16x16x32_bf16(     \
                        a[mm][kk], b[nn][kk], acc[4+mm][2+nn], 0, 0, 0);           \
        __builtin_amdgcn_s_setprio(0);                                             \
        __builtin_amdgcn_s_barrier();                                              \
        /* P4: re-read b0(4); stage A1(T+2); MFMA (1,0); boundary */               \
        _Pragma("unroll")                                                          \
        for (int nn = 0; nn < 2; ++nn) {                                           \
            b[nn][0] = *(const bf16x8*)(baseB0 + (BUF)*32768 + nn*2048);           \
            b[nn][1] = *(const bf16x8*)(baseB1 + (BUF)*32768 + nn*2048);           \
        }                                                                          \
        if ((T) + 2 < nk) {                                                        \
            GLL(pA01, As + (BUF)*16384 + cA01*512);                                \
            GLL(pA11, As + (BUF)*16384 + cA11*512);                                \
        }                                                                          \
        asm volatile("s_waitcnt lgkmcnt(0)" ::: "memory");                         \
        __builtin_amdgcn_s_barrier();                                              \
        __builtin_amdgcn_s_setprio(1);                                             \
        _Pragma("unroll")                                                          \
        for (int mm = 0; mm < 4; ++mm)                                             \
            _Pragma("unroll")                                                      \
            for (int nn = 0; nn < 2; ++nn)                                         \
                _Pragma("unroll")                                                  \
                for (int kk = 0; kk < 2; ++kk)                                     \
                    acc[4+mm][nn] = __builtin_amdgcn_mfma_f32_16x16x32_bf16(       \
                        a[mm][kk], b[nn][kk], acc[4+mm][nn], 0, 0, 0);             \
        __builtin_amdgcn_s_setprio(0);                                             \
        if ((T) == nk - 2)      asm volatile("s_waitcnt vmcnt(0)" ::: "memory");   \
        else if ((T) < nk - 2)  asm volatile("s_waitcnt vmcnt(6)" ::: "memory");   \
        __builtin_amdgcn_s_barrier();                                              \
        pA00 += 64; pA10 += 64; pA01 += 64; pA11 += 64;                            \
        pB00 += 64; pB10 += 64; pB01 += 64; pB11 += 64;                            \
    }

    for (int t = 0; t < nk; t += 2) {
        TILE_BODY(t, 0);
        TILE_BODY(t + 1, 1);
    }
#undef TILE_BODY

    // Epilogue: bias + maxpool4(cols) + rowsum, fused.
    // C/D frag mapping: col = lane&15, row = (lane>>4)*4 + reg  [m89-verified]
    float bias_n[4];
#pragma unroll
    for (int nn = 0; nn < 4; ++nn)
        bias_n[nn] = bias[bcol + wc * 64 + nn * 16 + lo];

#pragma unroll
    for (int mm = 0; mm < 8; ++mm) {
#pragma unroll
        for (int j = 0; j < 4; ++j) {
            float part = 0.f;
#pragma unroll
            for (int nn = 0; nn < 4; ++nn) {
                float v = acc[mm][nn][j] + bias_n[nn];
                v = fmaxf(v, __shfl_xor(v, 1));   // pool across col bit 0
                v = fmaxf(v, __shfl_xor(v, 2));   // pool across col bit 1
                part += v;                        // lane holds pooled[(lo>>2)]
            }
            part += __shfl_xor(part, 4);          // sum the 4 pool groups
            part += __shfl_xor(part, 8);
            if (lo == 0)
                atomicAdd(&out[brow + wr * 128 + mm * 16 + hi * 4 + j], part * 0.5f);
        }
    }
}

extern "C" void kernel_launch(void* const* d_in, const int* in_sizes, int n_in,
                              void* d_out, int out_size, void* d_ws, size_t ws_size,
                              hipStream_t stream) {
    const float* x = (const float*)d_in[0];
    const float* W = (const float*)d_in[1];
    const float* b = (const float*)d_in[2];
    float* out = (float*)d_out;

    const int N = in_sizes[2];             // out_f = 4096
    const int K = in_sizes[1] / N;         // in_f  = 2048
    const int M = in_sizes[0] / K;         // batch = 4096

    // Atomics accumulate into out -> must zero every call (graph replays).
    hipMemsetAsync(out, 0, (size_t)out_size * sizeof(float), stream);

    short* xb = (short*)d_ws;
    short* wb = xb + in_sizes[0];
    cvt_kernel<<<2048, 256, 0, stream>>>(x, W, (short*)d_ws,
                                         (long)in_sizes[0], (long)in_sizes[1]);

    dim3 grid(N / 256, M / 256);           // 256 blocks
    gemm_pool_kernel<<<grid, 512, 0, stream>>>(xb, wb, b, out, K);
}

// Round 10
// 91.088 us; speedup vs baseline: 1.3342x; 1.0434x over previous
//
#include <hip/hip_runtime.h>

// out = 0.5 * sum_over_pooled( maxpool4( x @ W^T + b ) )  -> (batch,) fp32
// x: (M=4096, K=2048) f32, W: (N=4096, K=2048) f32, b: (N,) f32, out: (M,) f32
// Strategy: cvt to bf16 in ws; 256x256 BK=64 8-wave MFMA GEMM.
// Schedule: ONE barrier per phase ({barrier; ds_reads; stage; lgkm0; MFMA}),
// quadrant order 00->01->11->10 with register-held b0/b1 (24 reads/tile),
// counted vmcnt(6) per tile, setprio, conflict-free XOR-swizzled LDS,
// launch_bounds(512,1) to avoid the 128-VGPR spill cap.
// Fused bias+maxpool4+rowsum epilogue with atomicAdd.

typedef float  f32x4   __attribute__((ext_vector_type(4)));
typedef short  bf16x8  __attribute__((ext_vector_type(8)));
typedef short  short4v __attribute__((ext_vector_type(4)));

__device__ __forceinline__ short f2bf(float f) {
    union { float f; unsigned u; } v; v.f = f;
    unsigned r = v.u + 0x7FFFu + ((v.u >> 16) & 1u);  // round-to-nearest-even
    return (short)(r >> 16);
}

__global__ void cvt_kernel(const float* __restrict__ x, const float* __restrict__ w,
                           short* __restrict__ out, long nx, long nw) {
    long total4 = (nx + nw) >> 2;
    long stride = (long)gridDim.x * blockDim.x;
    for (long i = (long)blockIdx.x * blockDim.x + threadIdx.x; i < total4; i += stride) {
        long e = i << 2;
        const float* src = (e < nx) ? (x + e) : (w + (e - nx));
        float4 v = *(const float4*)src;
        short4v s = { f2bf(v.x), f2bf(v.y), f2bf(v.z), f2bf(v.w) };
        *(short4v*)(out + e) = s;
    }
}

// LDS layout per 32KB buffer: row r (0..255), k-slice q (0..7 16B slices):
// short-offset = (r>>3)*512 + (r&7)*64 + (q^(r&7))*8.  Conflict-free
// ds_read_b128 (verified: SQ_LDS_BANK_CONFLICT=0). Staging linear per chunk
// (8 rows = 1KB = one wave-wide global_load_lds); global source applies the
// inverse swizzle: row = c*8 + (l>>3), q = (l&7)^(l>>3).
// Byte offsets: mm/nn +16 rows = +2048 B; b-half +32 rows = +4096 B;
// a-half +64 rows = +8192 B; buffer stride 32768 B.

#define GLL(gp, ldsp)                                                          \
    __builtin_amdgcn_global_load_lds(                                          \
        (const __attribute__((address_space(1))) unsigned int*)(gp),           \
        (__attribute__((address_space(3))) unsigned int*)(ldsp), 16, 0, 0)

__global__ __launch_bounds__(512, 1) void gemm_pool_kernel(
    const short* __restrict__ X, const short* __restrict__ W,
    const float* __restrict__ bias, float* __restrict__ out, int K)
{
    __shared__ short As[32768];   // 2 bufs x (256 rows x 64 k) = 64 KB
    __shared__ short Bs[32768];   // 64 KB

    const int tid  = threadIdx.x;
    const int lane = tid & 63;
    const int wid  = tid >> 6;     // 0..7
    const int wr   = wid >> 2;     // 0..1  (wave rows: 128 each)
    const int wc   = wid & 3;      // 0..3  (wave cols: 64 each)
    const int hi   = lane >> 4;    // frag k-slice part
    const int lo   = lane & 15;    // frag row part

    // XCD-aware bijective block swizzle (nwg = 256, divisible by 8).
    const int nwg  = gridDim.x * gridDim.y;
    const int bid  = blockIdx.y * gridDim.x + blockIdx.x;
    const int wgid = (bid & 7) * (nwg >> 3) + (bid >> 3);
    const int brow = (wgid / gridDim.x) * 256;
    const int bcol = (wgid % gridDim.x) * 256;
    const int nk   = K >> 6;       // BK=64 tiles; requires nk even, >= 4

    // ---- thread-constant ds_read bases (all loop reads = base + imm) ----
    const int slot0 = hi ^ (lo & 7);
    const int slot1 = (4 + hi) ^ (lo & 7);
    const char* baseA0 = (const char*)As + (((wr * 16 + (lo >> 3)) * 512 + (lo & 7) * 64 + slot0 * 8) << 1);
    const char* baseA1 = (const char*)As + (((wr * 16 + (lo >> 3)) * 512 + (lo & 7) * 64 + slot1 * 8) << 1);
    const char* baseB0 = (const char*)Bs + (((wc * 8  + (lo >> 3)) * 512 + (lo & 7) * 64 + slot0 * 8) << 1);
    const char* baseB1 = (const char*)Bs + (((wc * 8  + (lo >> 3)) * 512 + (lo & 7) * 64 + slot1 * 8) << 1);

    // ---- staging chunk ids and running global pointers (kt = 0) ----
    const int idx0 = wid * 2, idx1 = wid * 2 + 1;
    const int cA00 = (idx0 & 7) + ((idx0 >> 3) << 4), cA10 = (idx1 & 7) + ((idx1 >> 3) << 4);
    const int cA01 = cA00 + 8,                         cA11 = cA10 + 8;
    const int cB00 = ((idx0 >> 2) << 3) + (idx0 & 3),  cB10 = ((idx1 >> 2) << 3) + (idx1 & 3);
    const int cB01 = cB00 + 4,                         cB11 = cB10 + 4;
    const int grow = lane >> 3;
    const int gq8  = ((lane & 7) ^ (lane >> 3)) * 8;

    const short* pA00 = X + (size_t)(brow + cA00 * 8 + grow) * K + gq8;
    const short* pA10 = X + (size_t)(brow + cA10 * 8 + grow) * K + gq8;
    const short* pA01 = X + (size_t)(brow + cA01 * 8 + grow) * K + gq8;
    const short* pA11 = X + (size_t)(brow + cA11 * 8 + grow) * K + gq8;
    const short* pB00 = W + (size_t)(bcol + cB00 * 8 + grow) * K + gq8;
    const short* pB10 = W + (size_t)(bcol + cB10 * 8 + grow) * K + gq8;
    const short* pB01 = W + (size_t)(bcol + cB01 * 8 + grow) * K + gq8;
    const short* pB11 = W + (size_t)(bcol + cB11 * 8 + grow) * K + gq8;

    f32x4 acc[8][4] = {};
    bf16x8 a[4][2], b0[2][2], b1[2][2];

    // ---- prologue: tile 0 fully + {A0,B1,A1}(1) ----
    GLL(pA00, As + cA00 * 512); GLL(pA10, As + cA10 * 512);               // A0(0)
    GLL(pB00, Bs + cB00 * 512); GLL(pB10, Bs + cB10 * 512);               // B0(0)
    GLL(pB01, Bs + cB01 * 512); GLL(pB11, Bs + cB11 * 512);               // B1(0)
    GLL(pA01, As + cA01 * 512); GLL(pA11, As + cA11 * 512);               // A1(0)
    GLL(pA00 + 64, As + 16384 + cA00 * 512); GLL(pA10 + 64, As + 16384 + cA10 * 512); // A0(1)
    GLL(pB01 + 64, Bs + 16384 + cB01 * 512); GLL(pB11 + 64, Bs + 16384 + cB11 * 512); // B1(1)
    GLL(pA01 + 64, As + 16384 + cA01 * 512); GLL(pA11 + 64, As + 16384 + cA11 * 512); // A1(1)
    pA00 += 128; pA10 += 128; pA01 += 128; pA11 += 128;
    pB00 += 128; pB10 += 128; pB01 += 128; pB11 += 128;   // now at kt = 2
    asm volatile("s_waitcnt vmcnt(6)" ::: "memory");       // tile-0 complete

    // Phase = {barrier; ds_reads; stage; lgkm0; setprio; MFMA}. No post-MFMA
    // barrier: the next phase's barrier provides the WAR fence (each wave's
    // reads are lgkm0-drained before it arrives). Quadrants 00,01,11,10 with
    // b0 held P1->P4 and b1 held P2->P3 (P4 reads nothing).
#define TILE_BODY(T, BUF)                                                          \
    {                                                                              \
        /* P1: reads a0(8)+b0(4); stage B0(T+1)->other buf; MFMA (0,0) */          \
        __builtin_amdgcn_s_barrier();                                              \
        _Pragma("unroll")                                                          \
        for (int mm = 0; mm < 4; ++mm) {                                           \
            a[mm][0] = *(const bf16x8*)(baseA0 + (BUF)*32768 + mm*2048);           \
            a[mm][1] = *(const bf16x8*)(baseA1 + (BUF)*32768 + mm*2048);           \
        }                                                                          \
        _Pragma("unroll")                                                          \
        for (int nn = 0; nn < 2; ++nn) {                                           \
            b0[nn][0] = *(const bf16x8*)(baseB0 + (BUF)*32768 + nn*2048);          \
            b0[nn][1] = *(const bf16x8*)(baseB1 + (BUF)*32768 + nn*2048);          \
        }                                                                          \
        if ((T) + 1 < nk) {                                                        \
            GLL(pB00 - 64, Bs + (1-(BUF))*16384 + cB00*512);                       \
            GLL(pB10 - 64, Bs + (1-(BUF))*16384 + cB10*512);                       \
        }                                                                          \
        asm volatile("s_waitcnt lgkmcnt(0)" ::: "memory");                         \
        __builtin_amdgcn_s_setprio(1);                                             \
        _Pragma("unroll")                                                          \
        for (int mm = 0; mm < 4; ++mm)                                             \
            _Pragma("unroll")                                                      \
            for (int nn = 0; nn < 2; ++nn)                                         \
                _Pragma("unroll")                                                  \
                for (int kk = 0; kk < 2; ++kk)                                     \
                    acc[mm][nn] = __builtin_amdgcn_mfma_f32_16x16x32_bf16(         \
                        a[mm][kk], b0[nn][kk], acc[mm][nn], 0, 0, 0);              \
        __builtin_amdgcn_s_setprio(0);                                             \
        /* P2: reads b1(4); stage A0(T+2)->same buf; MFMA (0,1) */                 \
        __builtin_amdgcn_s_barrier();                                              \
        _Pragma("unroll")                                                          \
        for (int nn = 0; nn < 2; ++nn) {                                           \
            b1[nn][0] = *(const bf16x8*)(baseB0 + (BUF)*32768 + nn*2048 + 4096);   \
            b1[nn][1] = *(const bf16x8*)(baseB1 + (BUF)*32768 + nn*2048 + 4096);   \
        }                                                                          \
        if ((T) + 2 < nk) {                                                        \
            GLL(pA00, As + (BUF)*16384 + cA00*512);                                \
            GLL(pA10, As + (BUF)*16384 + cA10*512);                                \
        }                                                                          \
        asm volatile("s_waitcnt lgkmcnt(0)" ::: "memory");                         \
        __builtin_amdgcn_s_setprio(1);                                             \
        _Pragma("unroll")                                                          \
        for (int mm = 0; mm < 4; ++mm)                                             \
            _Pragma("unroll")                                                      \
            for (int nn = 0; nn < 2; ++nn)                                         \
                _Pragma("unroll")                                                  \
                for (int kk = 0; kk < 2; ++kk)                                     \
                    acc[mm][2+nn] = __builtin_amdgcn_mfma_f32_16x16x32_bf16(       \
                        a[mm][kk], b1[nn][kk], acc[mm][2+nn], 0, 0, 0);            \
        __builtin_amdgcn_s_setprio(0);                                             \
        /* P3: reads a1(8) [+8192B]; stage B1(T+2); MFMA (1,1) [b1 held] */        \
        __builtin_amdgcn_s_barrier();                                              \
        _Pragma("unroll")                                                          \
        for (int mm = 0; mm < 4; ++mm) {                                           \
            a[mm][0] = *(const bf16x8*)(baseA0 + (BUF)*32768 + mm*2048 + 8192);    \
            a[mm][1] = *(const bf16x8*)(baseA1 + (BUF)*32768 + mm*2048 + 8192);    \
        }                                                                          \
        if ((T) + 2 < nk) {                                                        \
            GLL(pB01, Bs + (BUF)*16384 + cB01*512);                                \
            GLL(pB11, Bs + (BUF)*16384 + cB11*512);                                \
        }                                                                          \
        asm volatile("s_waitcnt lgkmcnt(0)" ::: "memory");                         \
        __builtin_amdgcn_s_setprio(1);                                             \
        _Pragma("unroll")                                                          \
        for (int mm = 0; mm < 4; ++mm)                                             \
            _Pragma("unroll")                                                      \
            for (int nn = 0; nn < 2; ++nn)                                         \
                _Pragma("unroll")                                                  \
                for (int kk = 0; kk < 2; ++kk)                                     \
                    acc[4+mm][2+nn] = __builtin_amdgcn_mfma_f32_16x16x32_bf16(     \
                        a[mm][kk], b1[nn][kk], acc[4+mm][2+nn], 0, 0, 0);          \
        __builtin_amdgcn_s_setprio(0);                                             \
        /* P4: no reads; stage A1(T+2); MFMA (1,0) [b0 held]; boundary */          \
        __builtin_amdgcn_s_barrier();                                              \
        if ((T) + 2 < nk) {                                                        \
            GLL(pA01, As + (BUF)*16384 + cA01*512);                                \
            GLL(pA11, As + (BUF)*16384 + cA11*512);                                \
        }                                                                          \
        __builtin_amdgcn_s_setprio(1);                                             \
        _Pragma("unroll")                                                          \
        for (int mm = 0; mm < 4; ++mm)                                             \
            _Pragma("unroll")                                                      \
            for (int nn = 0; nn < 2; ++nn)                                         \
                _Pragma("unroll")                                                  \
                for (int kk = 0; kk < 2; ++kk)                                     \
                    acc[4+mm][nn] = __builtin_amdgcn_mfma_f32_16x16x32_bf16(       \
                        a[mm][kk], b0[nn][kk], acc[4+mm][nn], 0, 0, 0);            \
        __builtin_amdgcn_s_setprio(0);                                             \
        if ((T) == nk - 2)      asm volatile("s_waitcnt vmcnt(0)" ::: "memory");   \
        else if ((T) < nk - 2)  asm volatile("s_waitcnt vmcnt(6)" ::: "memory");   \
        pA00 += 64; pA10 += 64; pA01 += 64; pA11 += 64;                            \
        pB00 += 64; pB10 += 64; pB01 += 64; pB11 += 64;                            \
    }

    for (int t = 0; t < nk; t += 2) {
        TILE_BODY(t, 0);
        TILE_BODY(t + 1, 1);
    }
#undef TILE_BODY

    // Epilogue: bias + maxpool4(cols) + rowsum, fused.
    // C/D frag mapping: col = lane&15, row = (lane>>4)*4 + reg  [m89-verified]
    float bias_n[4];
#pragma unroll
    for (int nn = 0; nn < 4; ++nn)
        bias_n[nn] = bias[bcol + wc * 64 + nn * 16 + lo];

#pragma unroll
    for (int mm = 0; mm < 8; ++mm) {
#pragma unroll
        for (int j = 0; j < 4; ++j) {
            float part = 0.f;
#pragma unroll
            for (int nn = 0; nn < 4; ++nn) {
                float v = acc[mm][nn][j] + bias_n[nn];
                v = fmaxf(v, __shfl_xor(v, 1));   // pool across col bit 0
                v = fmaxf(v, __shfl_xor(v, 2));   // pool across col bit 1
                part += v;                        // lane holds pooled[(lo>>2)]
            }
            part += __shfl_xor(part, 4);          // sum the 4 pool groups
            part += __shfl_xor(part, 8);
            if (lo == 0)
                atomicAdd(&out[brow + wr * 128 + mm * 16 + hi * 4 + j], part * 0.5f);
        }
    }
}

extern "C" void kernel_launch(void* const* d_in, const int* in_sizes, int n_in,
                              void* d_out, int out_size, void* d_ws, size_t ws_size,
                              hipStream_t stream) {
    const float* x = (const float*)d_in[0];
    const float* W = (const float*)d_in[1];
    const float* b = (const float*)d_in[2];
    float* out = (float*)d_out;

    const int N = in_sizes[2];             // out_f = 4096
    const int K = in_sizes[1] / N;         // in_f  = 2048
    const int M = in_sizes[0] / K;         // batch = 4096

    // Atomics accumulate into out -> must zero every call (graph replays).
    hipMemsetAsync(out, 0, (size_t)out_size * sizeof(float), stream);

    short* xb = (short*)d_ws;
    short* wb = xb + in_sizes[0];
    cvt_kernel<<<2048, 256, 0, stream>>>(x, W, (short*)d_ws,
                                         (long)in_sizes[0], (long)in_sizes[1]);

    dim3 grid(N / 256, M / 256);           // 256 blocks
    gemm_pool_kernel<<<grid, 512, 0, stream>>>(xb, wb, b, out, K);
}